// Round 2
// baseline (537.367 us; speedup 1.0000x reference)
//
#include <hip/hip_runtime.h>
#include <hip/hip_bf16.h>

#define NN 4096
#define EPS 1e-5f

// ---------------- workspace layout (float offsets) ----------------
#define Q_OFF   0u              // [B][N][8]      131072
#define K_OFF   131072u         // [B][8][N]      131072
#define V_OFF   262144u         // [B][64][N]     1048576
#define O_OFF   1310720u        // PAM out [B][64][N]
#define Y_OFF   2359296u        // y
#define OC_OFF  3407872u        // CAM raw out
#define E_OFF   4456448u        // energy [B][64][64] 16384
#define AT_OFF  4472832u        // attn_c 16384
#define S2_OFF  4489216u        // sum2[64], sumsq2[64]
#define C1_OFF  4489344u        // A1[64], B1[64]
#define C2_OFF  4489472u        // A2[64], B2[64]

// ---------------- projections: q,k,v ----------------
__global__ __launch_bounds__(256) void proj_kernel(
    const float* __restrict__ x, const float* __restrict__ Wq, const float* __restrict__ bq,
    const float* __restrict__ Wk, const float* __restrict__ bk,
    const float* __restrict__ Wv, const float* __restrict__ bv,
    float* __restrict__ q, float* __restrict__ k, float* __restrict__ v) {
  __shared__ float sWq[8*64], sWk[8*64], sWv[64*64], sbq[8], sbk[8], sbv[64];
  int t = threadIdx.x;
  for (int i = t; i < 512; i += 256) { sWq[i] = Wq[i]; sWk[i] = Wk[i]; }
  for (int i = t; i < 4096; i += 256) sWv[i] = Wv[i];
  if (t < 64) sbv[t] = bv[t];
  if (t < 8) { sbq[t] = bq[t]; sbk[t] = bk[t]; }
  __syncthreads();
  int b = blockIdx.x >> 6;
  int n = ((blockIdx.x & 63) << 6) | (t & 63);
  int cg = t >> 6;
  float xv[64];
  #pragma unroll
  for (int c = 0; c < 64; ++c) xv[c] = x[(((b<<6)|c)<<12) | n];
  for (int c = cg*16; c < cg*16+16; ++c) {
    float acc = sbv[c];
    #pragma unroll
    for (int c2 = 0; c2 < 64; ++c2) acc += sWv[c*64 + c2] * xv[c2];
    v[(((b<<6)|c)<<12) | n] = acc;
  }
  if (cg == 0) {
    #pragma unroll
    for (int d = 0; d < 8; ++d) {
      float acc = sbq[d];
      #pragma unroll
      for (int c = 0; c < 64; ++c) acc += sWq[d*64+c] * xv[c];
      q[(((b<<12)|n)<<3) | d] = acc;
    }
  } else if (cg == 1) {
    #pragma unroll
    for (int d = 0; d < 8; ++d) {
      float acc = sbk[d];
      #pragma unroll
      for (int c = 0; c < 64; ++c) acc += sWk[d*64+c] * xv[c];
      k[(((b<<3)|d)<<12) | n] = acc;
    }
  }
}

// ---------------- flash attention (PAM) ----------------
// grid: 256 blocks = B * (N/64).  block: 256 threads.
__global__ __launch_bounds__(256) void attn_kernel(
    const float* __restrict__ q, const float* __restrict__ k,
    const float* __restrict__ v, float* __restrict__ o) {
  __shared__ float kst[64*12];   // [ni][d], pad 12 (48B rows, 16B aligned)
  __shared__ float vst[64*68];   // [ni][c], pad 68
  __shared__ float pst[64*68];   // [ni][m], pad 68
  __shared__ float mrun[64], lrun[64], alpha[64];
  __shared__ float red[4][64];

  const int b  = blockIdx.x >> 6;
  const int m0 = (blockIdx.x & 63) << 6;
  const int t  = threadIdx.x;
  const int tm = t & 63, tg = t >> 6;
  const int rm0 = (t >> 4) << 2;      // PV tile rows (m)
  const int rc0 = (t & 15) << 2;      // PV tile cols (c)

  // q row for this thread's score work (row tm), 8 floats
  const float4* qp = (const float4*)&q[(size_t)(((b<<12) | (m0 + tm)) << 3)];
  float4 q0 = qp[0], q1 = qp[1];

  if (t < 64) { mrun[t] = -1e30f; lrun[t] = 0.f; }
  float av[4][4];
  #pragma unroll
  for (int r = 0; r < 4; ++r)
    #pragma unroll
    for (int cc = 0; cc < 4; ++cc) av[r][cc] = 0.f;

  for (int n0 = 0; n0 < NN; n0 += 64) {
    __syncthreads();   // protect vst/pst/kst from previous iter readers
    // stage K chunk transposed: kst[ni][d]
    for (int i = t; i < 512; i += 256) {
      int ni = i & 63, d = i >> 6;
      kst[ni*12 + d] = k[(((b<<3)|d)<<12) + n0 + ni];
    }
    // stage V chunk transposed: vst[ni][c]
    for (int i = t; i < 4096; i += 256) {
      int ni = i & 63, c = i >> 6;
      vst[ni*68 + c] = v[(((b<<6)|c)<<12) + n0 + ni];
    }
    __syncthreads();
    // scores: thread (tm, tg) -> row tm, cols ni = tg*16 .. +16
    float sv[16];
    float lmax = -1e30f;
    #pragma unroll
    for (int j = 0; j < 16; ++j) {
      int ni = (tg << 4) + j;
      const float4* kp = (const float4*)&kst[ni*12];
      float4 ka = kp[0], kb = kp[1];
      float s = q0.x*ka.x + q0.y*ka.y + q0.z*ka.z + q0.w*ka.w
              + q1.x*kb.x + q1.y*kb.y + q1.z*kb.z + q1.w*kb.w;
      sv[j] = s;
      lmax = fmaxf(lmax, s);
    }
    red[tg][tm] = lmax;
    __syncthreads();
    if (t < 64) {
      float mx = fmaxf(fmaxf(red[0][t], red[1][t]), fmaxf(red[2][t], red[3][t]));
      float mnew = fmaxf(mrun[t], mx);
      alpha[t] = __expf(mrun[t] - mnew);
      mrun[t] = mnew;
    }
    __syncthreads();
    float mnew = mrun[tm];
    float lsum = 0.f;
    #pragma unroll
    for (int j = 0; j < 16; ++j) {
      float e = __expf(sv[j] - mnew);
      pst[((tg<<4)+j)*68 + tm] = e;
      lsum += e;
    }
    red[tg][tm] = lsum;
    __syncthreads();
    if (t < 64)
      lrun[t] = lrun[t]*alpha[t] + red[0][t]+red[1][t]+red[2][t]+red[3][t];
    // PV accumulate: av[r][cc] = av*alpha + sum_ni p[m][ni]*v[c][ni]
    float al[4];
    #pragma unroll
    for (int r = 0; r < 4; ++r) al[r] = alpha[rm0 + r];
    #pragma unroll
    for (int r = 0; r < 4; ++r)
      #pragma unroll
      for (int cc = 0; cc < 4; ++cc) av[r][cc] *= al[r];
    for (int ni = 0; ni < 64; ++ni) {
      float4 pv = *(const float4*)&pst[ni*68 + rm0];
      float4 vv = *(const float4*)&vst[ni*68 + rc0];
      av[0][0] += pv.x*vv.x; av[0][1] += pv.x*vv.y; av[0][2] += pv.x*vv.z; av[0][3] += pv.x*vv.w;
      av[1][0] += pv.y*vv.x; av[1][1] += pv.y*vv.y; av[1][2] += pv.y*vv.z; av[1][3] += pv.y*vv.w;
      av[2][0] += pv.z*vv.x; av[2][1] += pv.z*vv.y; av[2][2] += pv.z*vv.z; av[2][3] += pv.z*vv.w;
      av[3][0] += pv.w*vv.x; av[3][1] += pv.w*vv.y; av[3][2] += pv.w*vv.z; av[3][3] += pv.w*vv.w;
    }
  }
  __syncthreads();
  // epilogue: divide by l, route through LDS (reuse vst as [c][m]) for coalesced store
  float inv[4];
  #pragma unroll
  for (int r = 0; r < 4; ++r) inv[r] = 1.f / lrun[rm0 + r];
  #pragma unroll
  for (int r = 0; r < 4; ++r)
    #pragma unroll
    for (int cc = 0; cc < 4; ++cc)
      vst[(rc0+cc)*68 + (rm0+r)] = av[r][cc] * inv[r];
  __syncthreads();
  for (int it = 0; it < 16; ++it) {
    int i = it*256 + t;
    int m = i & 63, c = i >> 6;
    o[(((b<<6)|c)<<12) | (m0 + m)] = vst[c*68 + m];
  }
}

// ---------------- BN1 coefficients ----------------
__global__ __launch_bounds__(256) void bn1_coef_kernel(
    const float* __restrict__ o, const float* __restrict__ g,
    const float* __restrict__ w, const float* __restrict__ bb,
    float* __restrict__ coef) {
  int c = blockIdx.x, t = threadIdx.x;
  float s = 0.f, s2 = 0.f;
  for (int b = 0; b < 4; ++b) {
    const float* p = o + ((size_t)((b<<6)|c) << 12);
    for (int i = t; i < 4096; i += 256) { float vv = p[i]; s += vv; s2 += vv*vv; }
  }
  #pragma unroll
  for (int off = 32; off; off >>= 1) { s += __shfl_xor(s, off, 64); s2 += __shfl_xor(s2, off, 64); }
  __shared__ float rs[4], rs2[4];
  if ((t & 63) == 0) { rs[t>>6] = s; rs2[t>>6] = s2; }
  __syncthreads();
  if (t == 0) {
    s = rs[0]+rs[1]+rs[2]+rs[3]; s2 = rs2[0]+rs2[1]+rs2[2]+rs2[3];
    float m1 = s * (1.f/16384.f), m2 = s2 * (1.f/16384.f);
    float var = m2 - m1*m1;
    float gg = *g;
    float r = rsqrtf(gg*gg*var + EPS);
    float a = gg * r * w[c];
    coef[c] = a;
    coef[64+c] = bb[c] - m1*a;
  }
}

// ---------------- y = o*A1 + B1 + x ----------------
__global__ __launch_bounds__(256) void add_y_kernel(
    const float* __restrict__ o, const float* __restrict__ x,
    const float* __restrict__ coef, float* __restrict__ y) {
  int idx = blockIdx.x*256 + threadIdx.x;
  int c = (idx >> 12) & 63;
  y[idx] = o[idx]*coef[c] + coef[64+c] + x[idx];
}

// ---------------- CAM gram (partial, atomics) ----------------
__global__ __launch_bounds__(256) void gram_kernel(const float* __restrict__ y, float* __restrict__ energy) {
  __shared__ float yt[64*68];
  int b = blockIdx.x >> 4, sp = blockIdx.x & 15;
  int t = threadIdx.x;
  int tc = t >> 4, td = t & 15;
  float acc[4][4] = {{0}};
  for (int sub = 0; sub < 4; ++sub) {
    int n0 = (sp << 8) + (sub << 6);
    __syncthreads();
    for (int i = t; i < 1024; i += 256) {
      int c = i >> 4, nf = i & 15;
      float4 vv = *(const float4*)&y[(size_t)(((b<<6)|c)<<12) + n0 + (nf<<2)];
      *(float4*)&yt[c*68 + (nf<<2)] = vv;
    }
    __syncthreads();
    for (int nj = 0; nj < 16; ++nj) {
      float4 ya[4], yb[4];
      #pragma unroll
      for (int r = 0; r < 4; ++r) ya[r] = *(const float4*)&yt[((tc<<2)+r)*68 + (nj<<2)];
      #pragma unroll
      for (int ss = 0; ss < 4; ++ss) yb[ss] = *(const float4*)&yt[((td<<2)+ss)*68 + (nj<<2)];
      #pragma unroll
      for (int r = 0; r < 4; ++r)
        #pragma unroll
        for (int ss = 0; ss < 4; ++ss)
          acc[r][ss] += ya[r].x*yb[ss].x + ya[r].y*yb[ss].y + ya[r].z*yb[ss].z + ya[r].w*yb[ss].w;
    }
  }
  #pragma unroll
  for (int r = 0; r < 4; ++r)
    #pragma unroll
    for (int ss = 0; ss < 4; ++ss)
      atomicAdd(&energy[(((b<<6)|((tc<<2)+r))<<6) | ((td<<2)+ss)], acc[r][ss]);
}

// ---------------- CAM softmax (row-wise, 64 wide) ----------------
__global__ __launch_bounds__(64) void cam_softmax_kernel(
    const float* __restrict__ energy, float* __restrict__ attn) {
  int b = blockIdx.x >> 6, c = blockIdx.x & 63;
  int d = threadIdx.x;
  float e = energy[(((b<<6)|c)<<6) | d];
  float mn = e;
  #pragma unroll
  for (int off = 32; off; off >>= 1) mn = fminf(mn, __shfl_xor(mn, off, 64));
  // softmax(max_d(e) - e) == exp(min_d(e) - e) / sum
  float p = __expf(mn - e);
  float s = p;
  #pragma unroll
  for (int off = 32; off; off >>= 1) s += __shfl_xor(s, off, 64);
  attn[(((b<<6)|c)<<6) | d] = p / s;
}

// ---------------- out_c = attn_c @ y  (+ fused BN2 stats) ----------------
__global__ __launch_bounds__(256) void cam_apply_kernel(
    const float* __restrict__ attn, const float* __restrict__ y,
    float* __restrict__ oc, float* __restrict__ sums) {
  __shared__ float satt[64*68];
  int b = blockIdx.x >> 6;
  int n = ((blockIdx.x & 63) << 6) | (threadIdx.x & 63);
  int cg = threadIdx.x >> 6;
  for (int i = threadIdx.x; i < 4096; i += 256)
    satt[(i>>6)*68 + (i&63)] = attn[(b<<12) | i];
  __syncthreads();
  float yv[64];
  #pragma unroll
  for (int d = 0; d < 64; ++d) yv[d] = y[(((b<<6)|d)<<12) | n];
  for (int c = cg*16; c < cg*16+16; ++c) {
    float acc = 0.f;
    #pragma unroll
    for (int d4 = 0; d4 < 16; ++d4) {
      float4 avv = *(const float4*)&satt[c*68 + (d4<<2)];
      acc += avv.x*yv[d4*4] + avv.y*yv[d4*4+1] + avv.z*yv[d4*4+2] + avv.w*yv[d4*4+3];
    }
    oc[(((b<<6)|c)<<12) | n] = acc;
    float s1 = acc, s2 = acc*acc;
    #pragma unroll
    for (int off = 32; off; off >>= 1) { s1 += __shfl_xor(s1, off, 64); s2 += __shfl_xor(s2, off, 64); }
    if ((threadIdx.x & 63) == 0) { atomicAdd(&sums[c], s1); atomicAdd(&sums[64+c], s2); }
  }
}

// ---------------- BN2 coefficients ----------------
__global__ __launch_bounds__(64) void bn2_coef_kernel(
    const float* __restrict__ sums, const float* __restrict__ g,
    const float* __restrict__ w, const float* __restrict__ bb,
    float* __restrict__ coef) {
  int c = threadIdx.x;
  float m1 = sums[c] * (1.f/16384.f), m2 = sums[64+c] * (1.f/16384.f);
  float var = m2 - m1*m1;
  float gg = *g;
  float r = rsqrtf(gg*gg*var + EPS);
  float a = gg * r * w[c];
  coef[c] = a;
  coef[64+c] = bb[c] - m1*a;
}

// ---------------- final: out = oc*A2 + B2 + y (fp32) ----------------
__global__ __launch_bounds__(256) void final_kernel(
    const float* __restrict__ oc, const float* __restrict__ y,
    const float* __restrict__ coef, float* __restrict__ out) {
  int idx = blockIdx.x*256 + threadIdx.x;
  int c = (idx >> 12) & 63;
  out[idx] = oc[idx]*coef[c] + coef[64+c] + y[idx];
}

extern "C" void kernel_launch(void* const* d_in, const int* in_sizes, int n_in,
                              void* d_out, int out_size, void* d_ws, size_t ws_size,
                              hipStream_t stream) {
  (void)in_sizes; (void)n_in; (void)out_size; (void)ws_size;
  const float* x      = (const float*)d_in[0];
  const float* Wq     = (const float*)d_in[1];
  const float* bq     = (const float*)d_in[2];
  const float* Wk     = (const float*)d_in[3];
  const float* bk     = (const float*)d_in[4];
  const float* Wv     = (const float*)d_in[5];
  const float* bv     = (const float*)d_in[6];
  const float* gp     = (const float*)d_in[7];
  const float* bnp_w  = (const float*)d_in[8];
  const float* bnp_b  = (const float*)d_in[9];
  const float* gc     = (const float*)d_in[10];
  const float* bnc_w  = (const float*)d_in[11];
  const float* bnc_b  = (const float*)d_in[12];

  float* ws = (float*)d_ws;
  float* q   = ws + Q_OFF;
  float* k   = ws + K_OFF;
  float* v   = ws + V_OFF;
  float* o   = ws + O_OFF;
  float* y   = ws + Y_OFF;
  float* oc  = ws + OC_OFF;
  float* en  = ws + E_OFF;
  float* at  = ws + AT_OFF;
  float* s2b = ws + S2_OFF;
  float* c1  = ws + C1_OFF;
  float* c2  = ws + C2_OFF;

  // zero energy + attn + stat accumulators (contiguous region)
  hipMemsetAsync(en, 0, (16384u + 16384u + 128u) * sizeof(float), stream);

  proj_kernel<<<256, 256, 0, stream>>>(x, Wq, bq, Wk, bk, Wv, bv, q, k, v);
  attn_kernel<<<256, 256, 0, stream>>>(q, k, v, o);
  bn1_coef_kernel<<<64, 256, 0, stream>>>(o, gp, bnp_w, bnp_b, c1);
  add_y_kernel<<<4096, 256, 0, stream>>>(o, x, c1, y);
  gram_kernel<<<64, 256, 0, stream>>>(y, en);
  cam_softmax_kernel<<<256, 64, 0, stream>>>(en, at);
  cam_apply_kernel<<<256, 256, 0, stream>>>(at, y, oc, s2b);
  bn2_coef_kernel<<<1, 64, 0, stream>>>(s2b, gc, bnc_w, bnc_b, c2);
  final_kernel<<<4096, 256, 0, stream>>>(oc, y, c2, (float*)d_out);
}